// Round 1
// baseline (75.467 us; speedup 1.0000x reference)
//
#include <hip/hip_runtime.h>

#define GX 512
#define NF 32
#define XD 1024
#define NPIX (XD * XD)

__global__ __launch_bounds__(256) void tensor3d_mlp_kernel(
    const float* __restrict__ data,
    const float* __restrict__ W1, const float* __restrict__ b1,
    const float* __restrict__ W2, const float* __restrict__ b2,
    const float* __restrict__ W3, const float* __restrict__ b3,
    const int* __restrict__ x0v, const int* __restrict__ y0v,
    const int* __restrict__ x1v, const int* __restrict__ y1v,
    const float* __restrict__ lerp, float* __restrict__ out)
{
    const int p = blockIdx.x * blockDim.x + threadIdx.x;
    if (p >= NPIX) return;

    const int X0 = x0v[p], Y0 = y0v[p], X1 = x1v[p], Y1 = y1v[p];
    const float w0 = lerp[2 * p + 0];
    const float w1 = lerp[2 * p + 1];
    const float wa = (1.0f - w0) * (1.0f - w1);
    const float wb = w0 * (1.0f - w1);
    const float wc = (1.0f - w0) * w1;
    const float wd = w0 * w1;

    const float4* __restrict__ pa = (const float4*)(data + ((size_t)Y0 * GX + X0) * NF);
    const float4* __restrict__ pb = (const float4*)(data + ((size_t)Y0 * GX + X1) * NF);
    const float4* __restrict__ pc = (const float4*)(data + ((size_t)Y1 * GX + X0) * NF);
    const float4* __restrict__ pd = (const float4*)(data + ((size_t)Y1 * GX + X1) * NF);

    float feat[NF];
#pragma unroll
    for (int i = 0; i < NF / 4; ++i) {
        const float4 a = pa[i];
        const float4 b = pb[i];
        const float4 c = pc[i];
        const float4 d = pd[i];
        feat[4 * i + 0] = a.x * wa + b.x * wb + c.x * wc + d.x * wd;
        feat[4 * i + 1] = a.y * wa + b.y * wb + c.y * wc + d.y * wd;
        feat[4 * i + 2] = a.z * wa + b.z * wb + c.z * wc + d.z * wd;
        feat[4 * i + 3] = a.w * wa + b.w * wb + c.w * wc + d.w * wd;
    }

    // Layer 1: h1 = relu(feat @ W1 + b1)   W1 is [NF][NF], row i = input feature
    float h1[NF];
#pragma unroll
    for (int j = 0; j < NF; ++j) h1[j] = b1[j];
#pragma unroll
    for (int i = 0; i < NF; ++i) {
        const float f = feat[i];
#pragma unroll
        for (int j = 0; j < NF; ++j) h1[j] = fmaf(f, W1[i * NF + j], h1[j]);
    }
#pragma unroll
    for (int j = 0; j < NF; ++j) h1[j] = fmaxf(h1[j], 0.0f);

    // Layer 2: h2 = relu(h1 @ W2 + b2)
    float h2[NF];
#pragma unroll
    for (int j = 0; j < NF; ++j) h2[j] = b2[j];
#pragma unroll
    for (int i = 0; i < NF; ++i) {
        const float f = h1[i];
#pragma unroll
        for (int j = 0; j < NF; ++j) h2[j] = fmaf(f, W2[i * NF + j], h2[j]);
    }
#pragma unroll
    for (int j = 0; j < NF; ++j) h2[j] = fmaxf(h2[j], 0.0f);

    // Layer 3: out = h2 @ W3 + b3   (W3 is [NF][1])
    float o = b3[0];
#pragma unroll
    for (int i = 0; i < NF; ++i) o = fmaf(h2[i], W3[i], o);

    out[p] = o;
}

extern "C" void kernel_launch(void* const* d_in, const int* in_sizes, int n_in,
                              void* d_out, int out_size, void* d_ws, size_t ws_size,
                              hipStream_t stream) {
    // inputs (setup_inputs order): z, data, W1, b1, W2, b2, W3, b3, x0, y0, x1, y1, lerp_weights
    const float* data = (const float*)d_in[1];
    const float* W1   = (const float*)d_in[2];
    const float* b1   = (const float*)d_in[3];
    const float* W2   = (const float*)d_in[4];
    const float* b2   = (const float*)d_in[5];
    const float* W3   = (const float*)d_in[6];
    const float* b3   = (const float*)d_in[7];
    const int*   x0   = (const int*)d_in[8];
    const int*   y0   = (const int*)d_in[9];
    const int*   x1   = (const int*)d_in[10];
    const int*   y1   = (const int*)d_in[11];
    const float* lerp = (const float*)d_in[12];
    float* out = (float*)d_out;

    dim3 block(256);
    dim3 grid(NPIX / 256);
    hipLaunchKernelGGL(tensor3d_mlp_kernel, grid, block, 0, stream,
                       data, W1, b1, W2, b2, W3, b3, x0, y0, x1, y1, lerp, out);
}

// Round 3
// 47.815 us; speedup vs baseline: 1.5783x; 1.5783x over previous
//
#include <hip/hip_runtime.h>

#define GX 512
#define NF 32
#define XD 1024
#define NPIX (XD * XD)

typedef _Float16 half8 __attribute__((ext_vector_type(8)));
typedef __fp16  fp16x2 __attribute__((ext_vector_type(2)));
typedef float  floatx4 __attribute__((ext_vector_type(4)));

union PkU { fp16x2 h; unsigned u; };
union FragU { half8 h; unsigned u[4]; };

__device__ __forceinline__ unsigned pkrtz(float a, float b) {
    PkU x; x.h = __builtin_amdgcn_cvt_pkrtz(a, b); return x.u;
}

// One wave = 64 pixels. Swapped-operand MFMA: h^T[j][pix] = W^T @ feat^T.
// LDS buffer per wave, transposed layout hT[q][pixel]: word q = f16 pair of
// features (2q, 2q+1); row stride 68 words => all ds ops are 2-way bank (free).
__global__ __launch_bounds__(256) void tensor3d_mfma_kernel(
    const float* __restrict__ data,
    const float* __restrict__ W1, const float* __restrict__ b1,
    const float* __restrict__ W2, const float* __restrict__ b2,
    const float* __restrict__ W3, const float* __restrict__ b3,
    const int* __restrict__ x0v, const int* __restrict__ y0v,
    const int* __restrict__ x1v, const int* __restrict__ y1v,
    const float* __restrict__ lerp, float* __restrict__ out)
{
    __shared__ unsigned hT[4][16][68];

    const int tid  = threadIdx.x;
    const int wid  = tid >> 6;
    const int lane = tid & 63;
    const int col  = lane & 15;   // MFMA column (pixel within tile / jout row)
    const int grp  = lane >> 4;   // 16-lane group -> k-block
    const int waveBase = (blockIdx.x * 4 + wid) * 64;
    const int p = waveBase + lane;

    // ---------------- gather + bilinear interp (thread = pixel p) -----------
    const int X0 = x0v[p], Y0 = y0v[p], X1 = x1v[p], Y1 = y1v[p];
    const float2 lw = ((const float2*)lerp)[p];
    const float w0 = lw.x, w1 = lw.y;
    const float wA = (1.0f - w0) * (1.0f - w1);
    const float wB = w0 * (1.0f - w1);
    const float wC = (1.0f - w0) * w1;
    const float wD = w0 * w1;

    const float4* __restrict__ qa = (const float4*)(data + (Y0 * GX + X0) * NF);
    const float4* __restrict__ qb = (const float4*)(data + (Y0 * GX + X1) * NF);
    const float4* __restrict__ qc = (const float4*)(data + (Y1 * GX + X0) * NF);
    const float4* __restrict__ qd = (const float4*)(data + (Y1 * GX + X1) * NF);

    float fe[NF];
#pragma unroll
    for (int i = 0; i < NF / 4; ++i) {
        const float4 a = qa[i];
        const float4 b = qb[i];
        const float4 cc = qc[i];
        const float4 d = qd[i];
        fe[4*i+0] = a.x*wA + b.x*wB + cc.x*wC + d.x*wD;
        fe[4*i+1] = a.y*wA + b.y*wB + cc.y*wC + d.y*wD;
        fe[4*i+2] = a.z*wA + b.z*wB + cc.z*wC + d.z*wD;
        fe[4*i+3] = a.w*wA + b.w*wB + cc.w*wC + d.w*wD;
    }

    unsigned (* __restrict__ ht)[68] = hT[wid];

    // stage feat^T (f16 pairs), word q holds features (2q, 2q+1) of this pixel
#pragma unroll
    for (int q = 0; q < 16; ++q)
        ht[q][lane] = pkrtz(fe[2*q], fe[2*q+1]);

    // ---------------- layer 1: A-frags from W1^T, bias as C-in --------------
    half8 aw1[2]; floatx4 bia1[2];
#pragma unroll
    for (int jt = 0; jt < 2; ++jt) {
        FragU A;
#pragma unroll
        for (int w = 0; w < 4; ++w)
            A.u[w] = pkrtz(W1[(8*grp + 2*w    ) * NF + jt*16 + col],
                           W1[(8*grp + 2*w + 1) * NF + jt*16 + col]);
        aw1[jt] = A.h;
#pragma unroll
        for (int r = 0; r < 4; ++r) bia1[jt][r] = b1[jt*16 + 4*grp + r];
    }

    floatx4 d1[2][4];
#pragma unroll
    for (int pt = 0; pt < 4; ++pt) {
        FragU B;
#pragma unroll
        for (int w = 0; w < 4; ++w) B.u[w] = ht[4*grp + w][pt*16 + col];
        d1[0][pt] = __builtin_amdgcn_mfma_f32_16x16x32_f16(aw1[0], B.h, bia1[0], 0, 0, 0);
        d1[1][pt] = __builtin_amdgcn_mfma_f32_16x16x32_f16(aw1[1], B.h, bia1[1], 0, 0, 0);
    }

    // relu + write h1 back (overwrites feat words; same-wave DS is in-order)
#pragma unroll
    for (int pt = 0; pt < 4; ++pt)
#pragma unroll
        for (int jt = 0; jt < 2; ++jt) {
            const floatx4 v = d1[jt][pt];
            ht[8*jt + 2*grp + 0][pt*16 + col] = pkrtz(fmaxf(v[0], 0.f), fmaxf(v[1], 0.f));
            ht[8*jt + 2*grp + 1][pt*16 + col] = pkrtz(fmaxf(v[2], 0.f), fmaxf(v[3], 0.f));
        }

    // ---------------- layer 2 ----------------------------------------------
    half8 aw2[2]; floatx4 bia2[2];
#pragma unroll
    for (int jt = 0; jt < 2; ++jt) {
        FragU A;
#pragma unroll
        for (int w = 0; w < 4; ++w)
            A.u[w] = pkrtz(W2[(8*grp + 2*w    ) * NF + jt*16 + col],
                           W2[(8*grp + 2*w + 1) * NF + jt*16 + col]);
        aw2[jt] = A.h;
#pragma unroll
        for (int r = 0; r < 4; ++r) bia2[jt][r] = b2[jt*16 + 4*grp + r];
    }

    floatx4 d2[2][4];
#pragma unroll
    for (int pt = 0; pt < 4; ++pt) {
        FragU B;
#pragma unroll
        for (int w = 0; w < 4; ++w) B.u[w] = ht[4*grp + w][pt*16 + col];
        d2[0][pt] = __builtin_amdgcn_mfma_f32_16x16x32_f16(aw2[0], B.h, bia2[0], 0, 0, 0);
        d2[1][pt] = __builtin_amdgcn_mfma_f32_16x16x32_f16(aw2[1], B.h, bia2[1], 0, 0, 0);
    }

    // ---------------- layer 3: per-lane partial dot + cross-group reduce ----
    float w3v[8];
#pragma unroll
    for (int jt = 0; jt < 2; ++jt)
#pragma unroll
        for (int r = 0; r < 4; ++r) w3v[4*jt + r] = W3[jt*16 + 4*grp + r];

    float tot[4];
#pragma unroll
    for (int pt = 0; pt < 4; ++pt) {
        float s = 0.0f;
#pragma unroll
        for (int jt = 0; jt < 2; ++jt)
#pragma unroll
            for (int r = 0; r < 4; ++r)
                s = fmaf(fmaxf(d2[jt][pt][r], 0.0f), w3v[4*jt + r], s);
        s += __shfl_xor(s, 16, 64);
        s += __shfl_xor(s, 32, 64);
        tot[pt] = s;
    }

    // lane (grp g, col c) owns pixel g*16+c == lane -> pick tot[grp]
    const float o = (grp == 0) ? tot[0] : (grp == 1) ? tot[1] : (grp == 2) ? tot[2] : tot[3];
    out[p] = o + b3[0];
}

extern "C" void kernel_launch(void* const* d_in, const int* in_sizes, int n_in,
                              void* d_out, int out_size, void* d_ws, size_t ws_size,
                              hipStream_t stream) {
    // inputs: z, data, W1, b1, W2, b2, W3, b3, x0, y0, x1, y1, lerp_weights
    const float* data = (const float*)d_in[1];
    const float* W1   = (const float*)d_in[2];
    const float* b1   = (const float*)d_in[3];
    const float* W2   = (const float*)d_in[4];
    const float* b2   = (const float*)d_in[5];
    const float* W3   = (const float*)d_in[6];
    const float* b3   = (const float*)d_in[7];
    const int*   x0   = (const int*)d_in[8];
    const int*   y0   = (const int*)d_in[9];
    const int*   x1   = (const int*)d_in[10];
    const int*   y1   = (const int*)d_in[11];
    const float* lerp = (const float*)d_in[12];
    float* out = (float*)d_out;

    dim3 block(256);
    dim3 grid(NPIX / 256);
    hipLaunchKernelGGL(tensor3d_mfma_kernel, grid, block, 0, stream,
                       data, W1, b1, W2, b2, W3, b3, x0, y0, x1, y1, lerp, out);
}